// Round 3
// baseline (1078.138 us; speedup 1.0000x reference)
//
#include <hip/hip_runtime.h>
#include <hip/hip_bf16.h>
#include <math.h>

#define B_  2
#define S_  2048
#define H_  1024
#define NH_ 16
#define HD_ 64
#define BS_ (B_*S_)

typedef __bf16 bf16x8 __attribute__((ext_vector_type(8)));
typedef short  s16x8  __attribute__((ext_vector_type(8)));
typedef short  s16x4  __attribute__((ext_vector_type(4)));
typedef float  f32x4  __attribute__((ext_vector_type(4)));

__device__ __forceinline__ unsigned short f2b(float f) {
    __hip_bfloat16 h = __float2bfloat16(f);
    return __builtin_bit_cast(unsigned short, h);
}
__device__ __forceinline__ float sigmoidf_(float x) { return 1.0f / (1.0f + expf(-x)); }

__device__ __forceinline__ bf16x8 cat8(s16x4 a, s16x4 b) {
    s16x8 c = __builtin_shufflevector(a, b, 0, 1, 2, 3, 4, 5, 6, 7);
    return __builtin_bit_cast(bf16x8, c);
}
// convert 4 floats -> packed 4 bf16 shorts
__device__ __forceinline__ s16x4 cvt4(float4 v) {
    s16x4 r;
    r[0] = (short)f2b(v.x); r[1] = (short)f2b(v.y);
    r[2] = (short)f2b(v.z); r[3] = (short)f2b(v.w);
    return r;
}

// ---------------------------------------------------------------------------
// K1: memory gate (sigmoid(h . mg_w + mg_b)) and prosody gate per (b,s,nh).
// One wave per row; f32 exact.
// ---------------------------------------------------------------------------
__global__ __launch_bounds__(256) void gates_kernel(
    const float* __restrict__ hs, const float* __restrict__ prosody,
    const float* __restrict__ pg_w, const float* __restrict__ pg_b,
    const float* __restrict__ mg_w, const float* __restrict__ mg_b,
    float* __restrict__ gain, float* __restrict__ ms)
{
    int wave = threadIdx.x >> 6, lane = threadIdx.x & 63;
    int row = blockIdx.x * 4 + wave;           // row in [0, BS_)
    const float4* hr4 = (const float4*)(hs + (size_t)row * H_);
    const float4* mg4 = (const float4*)mg_w;
    float acc = 0.f;
#pragma unroll
    for (int i = 0; i < 4; ++i) {
        float4 h = hr4[lane + i * 64], m = mg4[lane + i * 64];
        acc += h.x * m.x + h.y * m.y + h.z * m.z + h.w * m.w;
    }
#pragma unroll
    for (int m = 32; m; m >>= 1) acc += __shfl_xor(acc, m);
    if (lane == 0)
        ms[row] = 1.0f + 0.5f * sigmoidf_(acc + mg_b[0]);
    if (lane < NH_) {
        float g = pg_b[lane];
#pragma unroll
        for (int i = 0; i < 4; ++i)
            g += prosody[row * 4 + i] * pg_w[i * NH_ + lane];
        gain[row * NH_ + lane] = 1.0f + sigmoidf_(g);   // store (1 + sigmoid)
    }
}

// ---------------------------------------------------------------------------
// K2: projection GEMM  C[4096,1024] = A @ W + bias  (bf16 MFMA 16x16x32)
// mode 0: Q from f32 hs (apply prosody gain, scatter bf16 [B,NH,S,HD])
// mode 1: K/V from f32 hs (scatter bf16 [B,NH,S,HD])
// mode 2: O from bf16 ctx ws -> f32 row-major [BS,H] out
// BM=BN=64, BK=32; 4 waves, each wave: 16 rows x 64 cols.
// ---------------------------------------------------------------------------
__global__ __launch_bounds__(256) void proj_kernel(
    const float* __restrict__ A32, const unsigned short* __restrict__ A16,
    const float* __restrict__ W, const float* __restrict__ bias,
    unsigned short* __restrict__ out16, float* __restrict__ out32,
    const float* __restrict__ gain, int mode)
{
    __shared__ short As[64 * 40];   // [m][k] bf16, stride 40
    __shared__ short Ws[64 * 40];   // transposed: [n][k] bf16
    int tid = threadIdx.x;
    int wave = tid >> 6, lane = tid & 63, quad = lane >> 4, l16 = lane & 15;
    int n0 = blockIdx.x * 64, m0 = blockIdx.y * 64;
    f32x4 acc[4] = {};

    for (int k0 = 0; k0 < H_; k0 += 32) {
        __syncthreads();
        {   // stage A tile 64x32 -> bf16 LDS
            int ar = tid >> 2, ac = (tid & 3) * 8;
            if (mode == 2) {
                const unsigned short* ap = A16 + (size_t)(m0 + ar) * H_ + k0 + ac;
                *(s16x4*)&As[ar * 40 + ac]     = *(const s16x4*)(ap);
                *(s16x4*)&As[ar * 40 + ac + 4] = *(const s16x4*)(ap + 4);
            } else {
                const float* ap = A32 + (size_t)(m0 + ar) * H_ + k0 + ac;
                *(s16x4*)&As[ar * 40 + ac]     = cvt4(*(const float4*)(ap));
                *(s16x4*)&As[ar * 40 + ac + 4] = cvt4(*(const float4*)(ap + 4));
            }
        }
        {   // stage W tile 32x64 transposed into Ws[n][k], f32 -> bf16
            int kr = tid >> 3, nc = (tid & 7) * 8;
            const float* wp = W + (size_t)(k0 + kr) * H_ + n0 + nc;
            s16x4 w0 = cvt4(*(const float4*)(wp));
            s16x4 w1 = cvt4(*(const float4*)(wp + 4));
#pragma unroll
            for (int j = 0; j < 4; ++j) Ws[(nc + j) * 40 + kr]     = w0[j];
#pragma unroll
            for (int j = 0; j < 4; ++j) Ws[(nc + 4 + j) * 40 + kr] = w1[j];
        }
        __syncthreads();
        int mrow = wave * 16 + l16;
        s16x4 a0 = *(const s16x4*)&As[mrow * 40 + quad * 8];
        s16x4 a1 = *(const s16x4*)&As[mrow * 40 + quad * 8 + 4];
        bf16x8 af = cat8(a0, a1);
#pragma unroll
        for (int nt = 0; nt < 4; ++nt) {
            int n = nt * 16 + l16;
            s16x4 b0 = *(const s16x4*)&Ws[n * 40 + quad * 8];
            s16x4 b1 = *(const s16x4*)&Ws[n * 40 + quad * 8 + 4];
            acc[nt] = __builtin_amdgcn_mfma_f32_16x16x32_bf16(af, cat8(b0, b1), acc[nt], 0, 0, 0);
        }
    }

    int mbase = m0 + wave * 16 + quad * 4;   // + r
#pragma unroll
    for (int nt = 0; nt < 4; ++nt) {
        int n = n0 + nt * 16 + l16;
        float bv = bias[n];
#pragma unroll
        for (int r = 0; r < 4; ++r) {
            int m = mbase + r;
            float v = acc[nt][r] + bv;
            if (mode == 2) {
                out32[(size_t)m * H_ + n] = v;
            } else {
                int b = m >> 11, s = m & (S_ - 1);
                int nh = n >> 6, hd = n & 63;
                if (mode == 0) v *= gain[m * NH_ + nh];       // (1 + sigmoid) pre-stored
                out16[(((size_t)(b * NH_ + nh)) * S_ + s) * HD_ + hd] = f2b(v);
            }
        }
    }
}

// ---------------------------------------------------------------------------
// K3: zero strictly-upper causal 64x64 tiles of attn_weights (f32).
// ---------------------------------------------------------------------------
__global__ __launch_bounds__(256) void zero_upper_kernel(float* __restrict__ attn)
{
    int kt = blockIdx.x, qt = blockIdx.y, bh = blockIdx.z;
    if (kt <= qt) return;
    float* p = attn + (size_t)bh * S_ * S_ + (size_t)(qt * 64) * S_ + kt * 64;
    int r = threadIdx.x >> 2, c = (threadIdx.x & 3) * 16;
    float4 z = {0.f, 0.f, 0.f, 0.f};
    float* q = p + (size_t)r * S_ + c;
    *(float4*)(q)      = z;
    *(float4*)(q + 4)  = z;
    *(float4*)(q + 8)  = z;
    *(float4*)(q + 12) = z;
}

// ---------------------------------------------------------------------------
// K4: fused causal attention per (bh, 64-row q-tile). Q/K/V in bf16 ws.
// Pass 1: row max + denominator. Pass 2: recompute, write f32 attn, PV.
// ---------------------------------------------------------------------------
__global__ __launch_bounds__(256) void attn_kernel(
    const unsigned short* __restrict__ qg, const unsigned short* __restrict__ kk,
    const unsigned short* __restrict__ vv, const float* __restrict__ ms,
    float* __restrict__ attn, unsigned short* __restrict__ ctx)
{
    __shared__ short Ks[64 * 72];       // [key][hd]
    __shared__ short Vt[64 * 72];       // [hd][key]
    __shared__ short Ps[4][16 * 72];    // per-wave P tile [row][key]
    __shared__ float mss[64];

    int tid = threadIdx.x;
    int wave = tid >> 6, lane = tid & 63, quad = lane >> 4, l16 = lane & 15;
    int qt = blockIdx.x, bh = blockIdx.y;
    int b = bh >> 4, h = bh & 15;

    const unsigned short* Qh = qg + (size_t)bh * S_ * HD_;
    const unsigned short* Kh = kk + (size_t)bh * S_ * HD_;
    const unsigned short* Vh = vv + (size_t)bh * S_ * HD_;
    float* attnh = attn + (size_t)bh * S_ * S_;

    if (tid < 64) mss[tid] = ms[b * S_ + qt * 64 + tid];

    // Q A-frags straight from global (row-major per head, contiguous k=hd)
    bf16x8 aq[2];
    {
        int qrow = qt * 64 + wave * 16 + l16;
#pragma unroll
        for (int c = 0; c < 2; ++c) {
            const unsigned short* qp = Qh + (size_t)qrow * HD_ + c * 32 + quad * 8;
            aq[c] = cat8(*(const s16x4*)qp, *(const s16x4*)(qp + 4));
        }
    }
    __syncthreads();
    float msr[4];
#pragma unroll
    for (int r = 0; r < 4; ++r) msr[r] = mss[wave * 16 + quad * 4 + r];
    int myrow0 = qt * 64 + wave * 16 + quad * 4;

    float m_run[4], l_run[4];
#pragma unroll
    for (int r = 0; r < 4; ++r) { m_run[r] = -1e30f; l_run[r] = 0.f; }

    // ---------------- pass 1: max + denominator ----------------
    for (int kt = 0; kt <= qt; ++kt) {
        __syncthreads();
        {   // stage K tile
            int key = tid >> 2, hc = (tid & 3) * 16;
            const unsigned short* kp = Kh + (size_t)(kt * 64 + key) * HD_ + hc;
            *(s16x4*)&Ks[key * 72 + hc]      = *(const s16x4*)(kp);
            *(s16x4*)&Ks[key * 72 + hc + 4]  = *(const s16x4*)(kp + 4);
            *(s16x4*)&Ks[key * 72 + hc + 8]  = *(const s16x4*)(kp + 8);
            *(s16x4*)&Ks[key * 72 + hc + 12] = *(const s16x4*)(kp + 12);
        }
        __syncthreads();
        float sv[4][4];
#pragma unroll
        for (int nt = 0; nt < 4; ++nt) {
            f32x4 sc = {};
            int n = nt * 16 + l16;
#pragma unroll
            for (int c = 0; c < 2; ++c) {
                s16x4 b0 = *(const s16x4*)&Ks[n * 72 + c * 32 + quad * 8];
                s16x4 b1 = *(const s16x4*)&Ks[n * 72 + c * 32 + quad * 8 + 4];
                sc = __builtin_amdgcn_mfma_f32_16x16x32_bf16(aq[c], cat8(b0, b1), sc, 0, 0, 0);
            }
#pragma unroll
            for (int r = 0; r < 4; ++r) {
                float s = sc[r] * 0.125f * msr[r];
                if (kt == qt) {
                    int col = kt * 64 + nt * 16 + l16;
                    if (col > myrow0 + r) s = -1e30f;
                }
                sv[nt][r] = s;
            }
        }
#pragma unroll
        for (int r = 0; r < 4; ++r) {
            float mt = fmaxf(fmaxf(sv[0][r], sv[1][r]), fmaxf(sv[2][r], sv[3][r]));
            mt = fmaxf(mt, __shfl_xor(mt, 1)); mt = fmaxf(mt, __shfl_xor(mt, 2));
            mt = fmaxf(mt, __shfl_xor(mt, 4)); mt = fmaxf(mt, __shfl_xor(mt, 8));
            float mn = fmaxf(m_run[r], mt);
            float lt = 0.f;
#pragma unroll
            for (int nt = 0; nt < 4; ++nt) lt += expf(sv[nt][r] - mn);
            lt += __shfl_xor(lt, 1); lt += __shfl_xor(lt, 2);
            lt += __shfl_xor(lt, 4); lt += __shfl_xor(lt, 8);
            l_run[r] = l_run[r] * expf(m_run[r] - mn) + lt;
            m_run[r] = mn;
        }
    }
    float inv_l[4];
#pragma unroll
    for (int r = 0; r < 4; ++r) inv_l[r] = 1.0f / l_run[r];

    // ---------------- pass 2: write attn + PV ----------------
    f32x4 oacc[4] = {};
    for (int kt = 0; kt <= qt; ++kt) {
        __syncthreads();
        {   // stage K tile + V tile (transposed)
            int key = tid >> 2, hc = (tid & 3) * 16;
            const unsigned short* kp = Kh + (size_t)(kt * 64 + key) * HD_ + hc;
            *(s16x4*)&Ks[key * 72 + hc]      = *(const s16x4*)(kp);
            *(s16x4*)&Ks[key * 72 + hc + 4]  = *(const s16x4*)(kp + 4);
            *(s16x4*)&Ks[key * 72 + hc + 8]  = *(const s16x4*)(kp + 8);
            *(s16x4*)&Ks[key * 72 + hc + 12] = *(const s16x4*)(kp + 12);
            const unsigned short* vp = Vh + (size_t)(kt * 64 + key) * HD_ + hc;
            s16x4 v0 = *(const s16x4*)(vp);
            s16x4 v1 = *(const s16x4*)(vp + 4);
            s16x4 v2 = *(const s16x4*)(vp + 8);
            s16x4 v3 = *(const s16x4*)(vp + 12);
#pragma unroll
            for (int j = 0; j < 4; ++j) Vt[(hc + j) * 72 + key]      = v0[j];
#pragma unroll
            for (int j = 0; j < 4; ++j) Vt[(hc + 4 + j) * 72 + key]  = v1[j];
#pragma unroll
            for (int j = 0; j < 4; ++j) Vt[(hc + 8 + j) * 72 + key]  = v2[j];
#pragma unroll
            for (int j = 0; j < 4; ++j) Vt[(hc + 12 + j) * 72 + key] = v3[j];
        }
        __syncthreads();
        // recompute scores, normalize, emit
#pragma unroll
        for (int nt = 0; nt < 4; ++nt) {
            f32x4 sc = {};
            int n = nt * 16 + l16;
#pragma unroll
            for (int c = 0; c < 2; ++c) {
                s16x4 b0 = *(const s16x4*)&Ks[n * 72 + c * 32 + quad * 8];
                s16x4 b1 = *(const s16x4*)&Ks[n * 72 + c * 32 + quad * 8 + 4];
                sc = __builtin_amdgcn_mfma_f32_16x16x32_bf16(aq[c], cat8(b0, b1), sc, 0, 0, 0);
            }
#pragma unroll
            for (int r = 0; r < 4; ++r) {
                float s = sc[r] * 0.125f * msr[r];
                if (kt == qt) {
                    int col = kt * 64 + nt * 16 + l16;
                    if (col > myrow0 + r) s = -1e30f;
                }
                float p = expf(s - m_run[r]) * inv_l[r];
                attnh[(size_t)(myrow0 + r) * S_ + kt * 64 + nt * 16 + l16] = p;
                Ps[wave][(quad * 4 + r) * 72 + nt * 16 + l16] = (short)f2b(p);
            }
        }
        // PV: P from LDS as A-frags, V^T from LDS as B-frags
#pragma unroll
        for (int c = 0; c < 2; ++c) {
            s16x4 p0 = *(const s16x4*)&Ps[wave][l16 * 72 + c * 32 + quad * 8];
            s16x4 p1 = *(const s16x4*)&Ps[wave][l16 * 72 + c * 32 + quad * 8 + 4];
            bf16x8 ap = cat8(p0, p1);
#pragma unroll
            for (int nt = 0; nt < 4; ++nt) {
                s16x4 b0 = *(const s16x4*)&Vt[(nt * 16 + l16) * 72 + c * 32 + quad * 8];
                s16x4 b1 = *(const s16x4*)&Vt[(nt * 16 + l16) * 72 + c * 32 + quad * 8 + 4];
                oacc[nt] = __builtin_amdgcn_mfma_f32_16x16x32_bf16(ap, cat8(b0, b1), oacc[nt], 0, 0, 0);
            }
        }
    }
    // write context [B,S,H] bf16 ws
#pragma unroll
    for (int nt = 0; nt < 4; ++nt) {
#pragma unroll
        for (int r = 0; r < 4; ++r) {
            int srow = myrow0 + r;
            ctx[((size_t)(b * S_ + srow)) * H_ + h * HD_ + nt * 16 + l16] = f2b(oacc[nt][r]);
        }
    }
}

// ---------------------------------------------------------------------------
extern "C" void kernel_launch(void* const* d_in, const int* in_sizes, int n_in,
                              void* d_out, int out_size, void* d_ws, size_t ws_size,
                              hipStream_t stream)
{
    const float* hs   = (const float*)d_in[0];
    const float* pros = (const float*)d_in[1];
    const float* q_w  = (const float*)d_in[2];
    const float* q_b  = (const float*)d_in[3];
    const float* k_w  = (const float*)d_in[4];
    const float* k_b  = (const float*)d_in[5];
    const float* v_w  = (const float*)d_in[6];
    const float* v_b  = (const float*)d_in[7];
    const float* o_w  = (const float*)d_in[8];
    const float* o_b  = (const float*)d_in[9];
    const float* pg_w = (const float*)d_in[10];
    const float* pg_b = (const float*)d_in[11];
    const float* mg_w = (const float*)d_in[12];
    const float* mg_b = (const float*)d_in[13];

    float* out0 = (float*)d_out;
    float* attn = out0 + (size_t)BS_ * H_;

    float* gain_ws = (float*)d_ws;                    // 256 KB
    float* ms_ws   = gain_ws + (size_t)BS_ * NH_;     // 16 KB
    unsigned short* q_ws   = (unsigned short*)(ms_ws + BS_);
    unsigned short* k_ws   = q_ws + (size_t)BS_ * H_;
    unsigned short* v_ws   = k_ws + (size_t)BS_ * H_;
    unsigned short* ctx_ws = v_ws + (size_t)BS_ * H_;

    gates_kernel<<<BS_ / 4, 256, 0, stream>>>(hs, pros, pg_w, pg_b, mg_w, mg_b, gain_ws, ms_ws);

    dim3 gg(H_ / 64, BS_ / 64);
    proj_kernel<<<gg, 256, 0, stream>>>(hs, nullptr, q_w, q_b, q_ws, nullptr, gain_ws, 0);
    proj_kernel<<<gg, 256, 0, stream>>>(hs, nullptr, k_w, k_b, k_ws, nullptr, gain_ws, 1);
    proj_kernel<<<gg, 256, 0, stream>>>(hs, nullptr, v_w, v_b, v_ws, nullptr, gain_ws, 1);

    zero_upper_kernel<<<dim3(S_ / 64, S_ / 64, B_ * NH_), 256, 0, stream>>>(attn);

    attn_kernel<<<dim3(S_ / 64, B_ * NH_), 256, 0, stream>>>(q_ws, k_ws, v_ws, ms_ws, attn, ctx_ws);

    proj_kernel<<<gg, 256, 0, stream>>>(nullptr, ctx_ws, o_w, o_b, nullptr, out0, gain_ws, 2);
}

// Round 4
// 900.495 us; speedup vs baseline: 1.1973x; 1.1973x over previous
//
#include <hip/hip_runtime.h>
#include <hip/hip_bf16.h>
#include <math.h>

#define B_  2
#define S_  2048
#define H_  1024
#define NH_ 16
#define HD_ 64
#define BS_ (B_*S_)

typedef __bf16 bf16x8 __attribute__((ext_vector_type(8)));
typedef short  s16x8  __attribute__((ext_vector_type(8)));
typedef short  s16x4  __attribute__((ext_vector_type(4)));
typedef float  f32x4  __attribute__((ext_vector_type(4)));

__device__ __forceinline__ unsigned short f2b(float f) {
    __hip_bfloat16 h = __float2bfloat16(f);
    return __builtin_bit_cast(unsigned short, h);
}
__device__ __forceinline__ float b2f(unsigned short u) {
    unsigned x = ((unsigned)u) << 16;
    return __uint_as_float(x);
}
__device__ __forceinline__ float sigmoidf_(float x) { return 1.0f / (1.0f + expf(-x)); }

__device__ __forceinline__ bf16x8 cat8(s16x4 a, s16x4 b) {
    s16x8 c = __builtin_shufflevector(a, b, 0, 1, 2, 3, 4, 5, 6, 7);
    return __builtin_bit_cast(bf16x8, c);
}
__device__ __forceinline__ s16x4 cvt4(float4 v) {
    s16x4 r;
    r[0] = (short)f2b(v.x); r[1] = (short)f2b(v.y);
    r[2] = (short)f2b(v.z); r[3] = (short)f2b(v.w);
    return r;
}
// async global->LDS, 16 bytes per lane; LDS dst = base + lane*16 (wave-uniform base)
__device__ __forceinline__ void glds16(const unsigned short* g, unsigned short* l) {
    __builtin_amdgcn_global_load_lds(
        (const __attribute__((address_space(1))) unsigned int*)g,
        (__attribute__((address_space(3))) unsigned int*)l, 16, 0, 0);
}

// ---------------------------------------------------------------------------
// K0a: convert hs f32 -> bf16 row-major [BS][H]
// ---------------------------------------------------------------------------
__global__ __launch_bounds__(256) void convert_hs_kernel(
    const float* __restrict__ src, unsigned short* __restrict__ dst)
{
    size_t i = ((size_t)blockIdx.x * 256 + threadIdx.x) * 8;
    float4 a = *(const float4*)(src + i);
    float4 b = *(const float4*)(src + i + 4);
    s16x8 o = __builtin_shufflevector(cvt4(a), cvt4(b), 0, 1, 2, 3, 4, 5, 6, 7);
    *(s16x8*)(dst + i) = o;
}

// ---------------------------------------------------------------------------
// K0b: transpose W [1024][1024] f32 -> Wt [1024][1024] bf16 (row n, col k).
// z: 0=q_w,1=k_w,2=v_w (into qkvWt rows z*1024+n), 3=o_w (into oWt).
// ---------------------------------------------------------------------------
__global__ __launch_bounds__(256) void transpose_w_kernel(
    const float* __restrict__ qw, const float* __restrict__ kw,
    const float* __restrict__ vw, const float* __restrict__ ow,
    unsigned short* __restrict__ qkvWt, unsigned short* __restrict__ oWt)
{
    __shared__ float T[64][65];
    int t = threadIdx.x;
    int k0 = blockIdx.x * 64, n0 = blockIdx.y * 64, z = blockIdx.z;
    const float* W = (z == 0) ? qw : (z == 1) ? kw : (z == 2) ? vw : ow;
#pragma unroll
    for (int p = 0; p < 4; ++p) {
        int row = p * 16 + (t >> 4);          // k within tile
        int cc = (t & 15) * 4;                // n within tile
        float4 v = *(const float4*)(W + (size_t)(k0 + row) * H_ + n0 + cc);
        T[row][cc] = v.x; T[row][cc+1] = v.y; T[row][cc+2] = v.z; T[row][cc+3] = v.w;
    }
    __syncthreads();
    unsigned short* dst = (z < 3) ? (qkvWt + ((size_t)z * H_) * H_) : oWt;
#pragma unroll
    for (int p = 0; p < 4; ++p) {
        int n = p * 16 + (t >> 4);            // n within tile
        int kc = (t & 15) * 4;                // k within tile
        float4 v = { T[kc][n], T[kc+1][n], T[kc+2][n], T[kc+3][n] };
        *(s16x4*)(dst + (size_t)(n0 + n) * H_ + k0 + kc) = cvt4(v);
    }
}

// ---------------------------------------------------------------------------
// K1: memory gate and prosody gate per (b,s,nh). One wave per row; f32 exact.
// ---------------------------------------------------------------------------
__global__ __launch_bounds__(256) void gates_kernel(
    const float* __restrict__ hs, const float* __restrict__ prosody,
    const float* __restrict__ pg_w, const float* __restrict__ pg_b,
    const float* __restrict__ mg_w, const float* __restrict__ mg_b,
    float* __restrict__ gain, float* __restrict__ ms)
{
    int wave = threadIdx.x >> 6, lane = threadIdx.x & 63;
    int row = blockIdx.x * 4 + wave;
    const float4* hr4 = (const float4*)(hs + (size_t)row * H_);
    const float4* mg4 = (const float4*)mg_w;
    float acc = 0.f;
#pragma unroll
    for (int i = 0; i < 4; ++i) {
        float4 h = hr4[lane + i * 64], m = mg4[lane + i * 64];
        acc += h.x * m.x + h.y * m.y + h.z * m.z + h.w * m.w;
    }
#pragma unroll
    for (int m = 32; m; m >>= 1) acc += __shfl_xor(acc, m);
    if (lane == 0)
        ms[row] = 1.0f + 0.5f * sigmoidf_(acc + mg_b[0]);
    if (lane < NH_) {
        float g = pg_b[lane];
#pragma unroll
        for (int i = 0; i < 4; ++i)
            g += prosody[row * 4 + i] * pg_w[i * NH_ + lane];
        gain[row * NH_ + lane] = 1.0f + sigmoidf_(g);
    }
}

// ---------------------------------------------------------------------------
// K2: m97-style GEMM  C[M][N] = A[M][1024] @ Bt[N][1024]^T + bias
// 128x128 tile, BK=64, global_load_lds 16B staging, 4 waves each 64x64.
// mode 0: fused QKV -> bf16 out [M][3072], gain on n<1024
// mode 1: O-proj    -> f32 out [M][1024]
// ---------------------------------------------------------------------------
__global__ __launch_bounds__(256) void gemm_kernel(
    const unsigned short* __restrict__ A, const unsigned short* __restrict__ Bt,
    const float* __restrict__ bias0, const float* __restrict__ bias1,
    const float* __restrict__ bias2, const float* __restrict__ gain,
    unsigned short* __restrict__ out16, float* __restrict__ out32,
    int ostride, int mode)
{
    __shared__ unsigned short As[128 * 64];   // [m][k] bf16, unpadded (glds layout)
    __shared__ unsigned short Bs[128 * 64];   // [n][k] bf16, unpadded
    int tid = threadIdx.x;
    int wave = tid >> 6, lane = tid & 63, quad = lane >> 4, l16 = lane & 15;
    int n0 = blockIdx.x * 128, m0 = blockIdx.y * 128;
    int wm = (wave & 1) * 64, wn = (wave >> 1) * 64;
    f32x4 acc[4][4] = {};

    int lrow = lane >> 3, lcol = (lane & 7) * 8;   // within a 1KB chunk: 8 rows x 64 cols
    for (int k0 = 0; k0 < H_; k0 += 64) {
        __syncthreads();
#pragma unroll
        for (int c = 0; c < 4; ++c) {
            int ch = wave * 4 + c;
            int row = ch * 8 + lrow;
            glds16(A  + (size_t)(m0 + row) * H_ + k0 + lcol, (unsigned short*)As + ch * 512);
            glds16(Bt + (size_t)(n0 + row) * H_ + k0 + lcol, (unsigned short*)Bs + ch * 512);
        }
        __syncthreads();
#pragma unroll
        for (int kc = 0; kc < 2; ++kc) {
            bf16x8 af[4], bfr[4];
#pragma unroll
            for (int i = 0; i < 4; ++i)
                af[i] = *(const bf16x8*)&As[(wm + i * 16 + l16) * 64 + kc * 32 + quad * 8];
#pragma unroll
            for (int j = 0; j < 4; ++j)
                bfr[j] = *(const bf16x8*)&Bs[(wn + j * 16 + l16) * 64 + kc * 32 + quad * 8];
#pragma unroll
            for (int i = 0; i < 4; ++i)
#pragma unroll
                for (int j = 0; j < 4; ++j)
                    acc[i][j] = __builtin_amdgcn_mfma_f32_16x16x32_bf16(af[i], bfr[j], acc[i][j], 0, 0, 0);
        }
    }

    int mat = n0 >> 10;   // uniform per block (128 | 1024)
    const float* bp = (mat == 0) ? bias0 : (mat == 1) ? bias1 : bias2;
#pragma unroll
    for (int j = 0; j < 4; ++j) {
        int n = n0 + wn + j * 16 + l16;
        float bv = bp[n & (H_ - 1)];
#pragma unroll
        for (int i = 0; i < 4; ++i) {
#pragma unroll
            for (int r = 0; r < 4; ++r) {
                int m = m0 + wm + i * 16 + quad * 4 + r;
                float v = acc[i][j][r] + bv;
                if (mode == 0) {
                    if (n < H_) v *= gain[m * NH_ + (n >> 6)];
                    out16[(size_t)m * ostride + n] = f2b(v);
                } else {
                    out32[(size_t)m * ostride + n] = v;
                }
            }
        }
    }
}

// ---------------------------------------------------------------------------
// K3: zero strictly-upper causal 64x64 tiles of attn_weights (f32).
// ---------------------------------------------------------------------------
__global__ __launch_bounds__(256) void zero_upper_kernel(float* __restrict__ attn)
{
    int kt = blockIdx.x, qt = blockIdx.y, bh = blockIdx.z;
    if (kt <= qt) return;
    float* p = attn + (size_t)bh * S_ * S_ + (size_t)(qt * 64) * S_ + kt * 64;
    int r = threadIdx.x >> 2, c = (threadIdx.x & 3) * 16;
    float4 z = {0.f, 0.f, 0.f, 0.f};
    float* q = p + (size_t)r * S_ + c;
    *(float4*)(q)      = z;
    *(float4*)(q + 4)  = z;
    *(float4*)(q + 8)  = z;
    *(float4*)(q + 12) = z;
}

// ---------------------------------------------------------------------------
// K4: fused causal attention per (bh, 64-row q-tile).
// QKV packed [B*S][3072] bf16 (q|k|v). No-max softmax (scores bounded small):
// pass 1 = QK^T + exp + rowsum only; pass 2 = normalize, write f32 attn
// (vectorized via Ps readback), PV accumulate.
// ---------------------------------------------------------------------------
__global__ __launch_bounds__(256) void attn_kernel(
    const unsigned short* __restrict__ qkv, const float* __restrict__ ms,
    float* __restrict__ attn, unsigned short* __restrict__ ctx)
{
    __shared__ short Ks[64 * 72];       // [key][hd]
    __shared__ short Vt[64 * 72];       // [hd][key]
    __shared__ short Ps[4][16 * 72];    // per-wave normalized P tile [row][key]
    __shared__ float mss[64];

    int tid = threadIdx.x;
    int wave = tid >> 6, lane = tid & 63, quad = lane >> 4, l16 = lane & 15;
    int qt = blockIdx.x, bh = blockIdx.y;
    int b = bh >> 4, h = bh & 15;

    const unsigned short* base = qkv + (size_t)b * S_ * 3072;
    int offQ = h * 64, offK = 1024 + h * 64, offV = 2048 + h * 64;
    float* attnh = attn + (size_t)bh * S_ * S_;

    if (tid < 64) mss[tid] = ms[b * S_ + qt * 64 + tid];

    bf16x8 aq[2];
    {
        int qrow = qt * 64 + wave * 16 + l16;
#pragma unroll
        for (int c = 0; c < 2; ++c) {
            const unsigned short* qp = base + (size_t)qrow * 3072 + offQ + c * 32 + quad * 8;
            aq[c] = cat8(*(const s16x4*)qp, *(const s16x4*)(qp + 4));
        }
    }
    __syncthreads();
    float escale[4];
#pragma unroll
    for (int r = 0; r < 4; ++r) escale[r] = 0.125f * mss[wave * 16 + quad * 4 + r];
    int myrow0 = qt * 64 + wave * 16 + quad * 4;

    float l_run[4] = {0.f, 0.f, 0.f, 0.f};

    // ---------------- pass 1: denominators only ----------------
    for (int kt = 0; kt <= qt; ++kt) {
        __syncthreads();
        {   // stage K tile
            int key = tid >> 2, hc = (tid & 3) * 16;
            const unsigned short* kp = base + (size_t)(kt * 64 + key) * 3072 + offK + hc;
            *(s16x8*)&Ks[key * 72 + hc]     = *(const s16x8*)(kp);
            *(s16x8*)&Ks[key * 72 + hc + 8] = *(const s16x8*)(kp + 8);
        }
        __syncthreads();
        float esum[4] = {0.f, 0.f, 0.f, 0.f};
#pragma unroll
        for (int nt = 0; nt < 4; ++nt) {
            f32x4 sc = {};
            int n = nt * 16 + l16;
#pragma unroll
            for (int c = 0; c < 2; ++c) {
                s16x4 b0 = *(const s16x4*)&Ks[n * 72 + c * 32 + quad * 8];
                s16x4 b1 = *(const s16x4*)&Ks[n * 72 + c * 32 + quad * 8 + 4];
                sc = __builtin_amdgcn_mfma_f32_16x16x32_bf16(aq[c], cat8(b0, b1), sc, 0, 0, 0);
            }
            int col = kt * 64 + nt * 16 + l16;
#pragma unroll
            for (int r = 0; r < 4; ++r) {
                float e = (kt == qt && col > myrow0 + r) ? 0.f : __expf(sc[r] * escale[r]);
                esum[r] += e;
            }
        }
#pragma unroll
        for (int r = 0; r < 4; ++r) {
            float lt = esum[r];
            lt += __shfl_xor(lt, 1); lt += __shfl_xor(lt, 2);
            lt += __shfl_xor(lt, 4); lt += __shfl_xor(lt, 8);
            l_run[r] += lt;
        }
    }
    float inv_l[4];
#pragma unroll
    for (int r = 0; r < 4; ++r) inv_l[r] = 1.0f / l_run[r];

    // ---------------- pass 2: write attn + PV ----------------
    f32x4 oacc[4] = {};
    for (int kt = 0; kt <= qt; ++kt) {
        __syncthreads();
        {   // stage K + V (V transposed)
            int key = tid >> 2, hc = (tid & 3) * 16;
            const unsigned short* kp = base + (size_t)(kt * 64 + key) * 3072 + offK + hc;
            *(s16x8*)&Ks[key * 72 + hc]     = *(const s16x8*)(kp);
            *(s16x8*)&Ks[key * 72 + hc + 8] = *(const s16x8*)(kp + 8);
            const unsigned short* vp = base + (size_t)(kt * 64 + key) * 3072 + offV + hc;
            s16x4 v0 = *(const s16x4*)(vp);
            s16x4 v1 = *(const s16x4*)(vp + 4);
            s16x4 v2 = *(const s16x4*)(vp + 8);
            s16x4 v3 = *(const s16x4*)(vp + 12);
#pragma unroll
            for (int j = 0; j < 4; ++j) Vt[(hc + j) * 72 + key]      = v0[j];
#pragma unroll
            for (int j = 0; j < 4; ++j) Vt[(hc + 4 + j) * 72 + key]  = v1[j];
#pragma unroll
            for (int j = 0; j < 4; ++j) Vt[(hc + 8 + j) * 72 + key]  = v2[j];
#pragma unroll
            for (int j = 0; j < 4; ++j) Vt[(hc + 12 + j) * 72 + key] = v3[j];
        }
        __syncthreads();
#pragma unroll
        for (int nt = 0; nt < 4; ++nt) {
            f32x4 sc = {};
            int n = nt * 16 + l16;
#pragma unroll
            for (int c = 0; c < 2; ++c) {
                s16x4 b0 = *(const s16x4*)&Ks[n * 72 + c * 32 + quad * 8];
                s16x4 b1 = *(const s16x4*)&Ks[n * 72 + c * 32 + quad * 8 + 4];
                sc = __builtin_amdgcn_mfma_f32_16x16x32_bf16(aq[c], cat8(b0, b1), sc, 0, 0, 0);
            }
            int col = kt * 64 + nt * 16 + l16;
#pragma unroll
            for (int r = 0; r < 4; ++r) {
                float p = (kt == qt && col > myrow0 + r) ? 0.f
                          : __expf(sc[r] * escale[r]) * inv_l[r];
                Ps[wave][(quad * 4 + r) * 72 + nt * 16 + l16] = (short)f2b(p);
            }
        }
        // vectorized attn store: read back Ps rows, 4 f32 per lane per chunk
#pragma unroll
        for (int c = 0; c < 4; ++c) {
            int row_local = c * 4 + quad;
            s16x4 p4 = *(const s16x4*)&Ps[wave][row_local * 72 + l16 * 4];
            float4 f;
            f.x = b2f((unsigned short)p4[0]); f.y = b2f((unsigned short)p4[1]);
            f.z = b2f((unsigned short)p4[2]); f.w = b2f((unsigned short)p4[3]);
            int row_s = qt * 64 + wave * 16 + row_local;
            *(float4*)(attnh + (size_t)row_s * S_ + kt * 64 + l16 * 4) = f;
        }
        // PV: P (normalized) from LDS as A-frags, V^T as B-frags
#pragma unroll
        for (int c = 0; c < 2; ++c) {
            s16x4 p0 = *(const s16x4*)&Ps[wave][l16 * 72 + c * 32 + quad * 8];
            s16x4 p1 = *(const s16x4*)&Ps[wave][l16 * 72 + c * 32 + quad * 8 + 4];
            bf16x8 ap = cat8(p0, p1);
#pragma unroll
            for (int nt = 0; nt < 4; ++nt) {
                s16x4 b0 = *(const s16x4*)&Vt[(nt * 16 + l16) * 72 + c * 32 + quad * 8];
                s16x4 b1 = *(const s16x4*)&Vt[(nt * 16 + l16) * 72 + c * 32 + quad * 8 + 4];
                oacc[nt] = __builtin_amdgcn_mfma_f32_16x16x32_bf16(ap, cat8(b0, b1), oacc[nt], 0, 0, 0);
            }
        }
    }
    // write context [B,S,H] bf16 ws
#pragma unroll
    for (int nt = 0; nt < 4; ++nt) {
#pragma unroll
        for (int r = 0; r < 4; ++r) {
            int srow = myrow0 + r;
            ctx[((size_t)(b * S_ + srow)) * H_ + h * HD_ + nt * 16 + l16] = f2b(oacc[nt][r]);
        }
    }
}

// ---------------------------------------------------------------------------
extern "C" void kernel_launch(void* const* d_in, const int* in_sizes, int n_in,
                              void* d_out, int out_size, void* d_ws, size_t ws_size,
                              hipStream_t stream)
{
    const float* hs   = (const float*)d_in[0];
    const float* pros = (const float*)d_in[1];
    const float* q_w  = (const float*)d_in[2];
    const float* q_b  = (const float*)d_in[3];
    const float* k_w  = (const float*)d_in[4];
    const float* k_b  = (const float*)d_in[5];
    const float* v_w  = (const float*)d_in[6];
    const float* v_b  = (const float*)d_in[7];
    const float* o_w  = (const float*)d_in[8];
    const float* o_b  = (const float*)d_in[9];
    const float* pg_w = (const float*)d_in[10];
    const float* pg_b = (const float*)d_in[11];
    const float* mg_w = (const float*)d_in[12];
    const float* mg_b = (const float*)d_in[13];

    float* out0 = (float*)d_out;
    float* attn = out0 + (size_t)BS_ * H_;

    float* gain_ws = (float*)d_ws;                                     // 256 KB
    float* ms_ws   = gain_ws + (size_t)BS_ * NH_;                      // 16 KB
    unsigned short* hs16   = (unsigned short*)(ms_ws + BS_);           // 8 MB
    unsigned short* qkvWt  = hs16 + (size_t)BS_ * H_;                  // 6 MB
    unsigned short* oWt    = qkvWt + (size_t)3 * H_ * H_;              // 2 MB
    unsigned short* qkv16  = oWt + (size_t)H_ * H_;                    // 24 MB
    unsigned short* ctx16  = qkv16 + (size_t)BS_ * 3 * H_;             // 8 MB

    convert_hs_kernel<<<(BS_ * H_) / (256 * 8), 256, 0, stream>>>(hs, hs16);
    transpose_w_kernel<<<dim3(16, 16, 4), 256, 0, stream>>>(q_w, k_w, v_w, o_w, qkvWt, oWt);
    gates_kernel<<<BS_ / 4, 256, 0, stream>>>(hs, pros, pg_w, pg_b, mg_w, mg_b, gain_ws, ms_ws);

    // fused QKV: [4096][1024] @ [3072][1024]^T -> bf16 [4096][3072]
    gemm_kernel<<<dim3(3 * H_ / 128, BS_ / 128), 256, 0, stream>>>(
        hs16, qkvWt, q_b, k_b, v_b, gain_ws, qkv16, nullptr, 3 * H_, 0);

    zero_upper_kernel<<<dim3(S_ / 64, S_ / 64, B_ * NH_), 256, 0, stream>>>(attn);

    attn_kernel<<<dim3(S_ / 64, B_ * NH_), 256, 0, stream>>>(qkv16, ms_ws, attn, ctx16);

    // O-proj: [4096][1024] @ [1024][1024]^T -> f32 out0
    gemm_kernel<<<dim3(H_ / 128, BS_ / 128), 256, 0, stream>>>(
        ctx16, oWt, o_b, nullptr, nullptr, nullptr, nullptr, out0, H_, 1);
}